// Round 1
// baseline (153.554 us; speedup 1.0000x reference)
//
#include <hip/hip_runtime.h>

// BaconAdditionReasoner: y[b,k] = norm_k( 1 - prod_{i+j==k} (1 - clamp(min(p1p_i, p2p_j))) )
// where p1p = p1 @ minmax_norm(W1), p2p = p2 @ minmax_norm(W2).
//
// R2 algebra (kept): 1 - min(ap_i,bp_j) = max(1-ap_i, 1-bp_j); A_i = 1 - a@W1n
// folded into the matmul; clamps dropped (s in [0,1], error << threshold).
// R4 (kept): wn in LDS, broadcast ds_read; prep fused into every block (t<20).
//
// R5: input loads were the hidden bottleneck. Old pattern: 5x float2 per array
// at 40B lane stride -> each wave-instr touches ~40 cache lines for 512B of
// payload (~10x line-transaction inflation, ~800 req/wave). At ~1 line-req/cyc
// /CU that's ~21us/CU of request processing - the gap between 49us measured and
// VALU(10)+LDS(13)+HBM-bytes(19-26) phases. Fix: stage the block's input panel
// (2x10240B) into LDS via fully-coalesced float4 loads (lane l -> base+16*l,
// 16 req/instr), then read rows from LDS (b64 @ 40B stride = 4-way alias,
// ~1.6x on a tiny term). s_buf is a union: inputs until the k-loop consumes
// them, output staging after a barrier. Also removes the compiler's
// register-starved load-sinking (VGPR=32 forced global float2 loads into the
// k-loop, serializing global latency per wave).

#define NBLOCKS 4096  // 4096 * 256 = 1048576 = B

__global__ __launch_bounds__(256) void bacon_main(
    const float* __restrict__ p1, const float* __restrict__ p2,
    const float* __restrict__ W1, const float* __restrict__ W2,
    float* __restrict__ out)
{
    // [0,2560) = p1 rows (256x10 f32), [2560,5120) = p2 rows; reused for output
    // staging (4864 floats) after inputs are consumed. 20480B + 960B -> 7 blk/CU.
    __shared__ __align__(16) float s_buf[5120];
    __shared__ __align__(16) float s_w[240];   // wn: [2][10][12] stride-12 padded

    const int t = threadIdx.x;
    const int blk = blockIdx.x;

    // ---- coalesced input stage: 1280 float4 (two 10240B panels), 5/thread ----
    // idx = t + 256e; waves are uniform vs the 640 boundary (640 = 10*64).
    const float4* g1 = (const float4*)(p1 + (size_t)blk * 2560);
    const float4* g2 = (const float4*)(p2 + (size_t)blk * 2560);
    float4 v[5];
    #pragma unroll
    for (int e = 0; e < 5; ++e) {
        int idx = t + e * 256;
        v[e] = (idx < 640) ? g1[idx] : g2[idx - 640];
    }

    // ---- fused prep: threads 0..19 minmax-normalize one W row into LDS ----
    if (t < 20) {
        const float* row = ((t < 10) ? W1 : W2) + (t % 10) * 10;
        float r[10];
        #pragma unroll
        for (int i = 0; i < 10; ++i) r[i] = row[i];
        float lo = r[0], hi = r[0];
        #pragma unroll
        for (int i = 1; i < 10; ++i) {
            lo = fminf(lo, r[i]);
            hi = fmaxf(hi, r[i]);
        }
        float inv = 1.0f / (hi - lo + 1e-8f);
        float* o = s_w + ((t < 10) ? 0 : 120) + (t % 10) * 12;
        #pragma unroll
        for (int i = 0; i < 10; ++i) o[i] = (r[i] - lo) * inv;
        o[10] = 0.0f; o[11] = 0.0f;
    }

    // ---- land the staged panel in LDS (coalesced b128 writes) ----
    {
        float4* sb4 = (float4*)s_buf;
        #pragma unroll
        for (int e = 0; e < 5; ++e) sb4[t + e * 256] = v[e];
    }
    __syncthreads();

    // ---- own row from LDS: b64 reads, 40B stride (4-way alias, ~free) ----
    float a[10], b[10];
    {
        const float2* r1 = (const float2*)s_buf + t * 5;
        const float2* r2 = (const float2*)(s_buf + 2560) + t * 5;
        #pragma unroll
        for (int e = 0; e < 5; ++e) {
            float2 va = r1[e];
            float2 vb = r2[e];
            a[2 * e] = va.x; a[2 * e + 1] = va.y;
            b[2 * e] = vb.x; b[2 * e + 1] = vb.y;
        }
    }

    // ---- A_i = 1 - a @ W1n, B_j = 1 - b @ W2n; wn via LDS broadcast float4 ----
    float A[10], Bv[10];
    #pragma unroll
    for (int i = 0; i < 10; ++i) { A[i] = 1.0f; Bv[i] = 1.0f; }
    #pragma unroll
    for (int k = 0; k < 10; ++k) {
        float ak = a[k], bk = b[k];
        const float4* w1q = (const float4*)(s_w + k * 12);          // 48B-aligned
        const float4* w2q = (const float4*)(s_w + 120 + k * 12);
        float4 u0 = w1q[0], u1 = w1q[1];
        float2 u2 = *(const float2*)(s_w + k * 12 + 8);
        float4 v0 = w2q[0], v1 = w2q[1];
        float2 v2 = *(const float2*)(s_w + 120 + k * 12 + 8);
        A[0] = fmaf(-ak, u0.x, A[0]); A[1] = fmaf(-ak, u0.y, A[1]);
        A[2] = fmaf(-ak, u0.z, A[2]); A[3] = fmaf(-ak, u0.w, A[3]);
        A[4] = fmaf(-ak, u1.x, A[4]); A[5] = fmaf(-ak, u1.y, A[5]);
        A[6] = fmaf(-ak, u1.z, A[6]); A[7] = fmaf(-ak, u1.w, A[7]);
        A[8] = fmaf(-ak, u2.x, A[8]); A[9] = fmaf(-ak, u2.y, A[9]);
        Bv[0] = fmaf(-bk, v0.x, Bv[0]); Bv[1] = fmaf(-bk, v0.y, Bv[1]);
        Bv[2] = fmaf(-bk, v0.z, Bv[2]); Bv[3] = fmaf(-bk, v0.w, Bv[3]);
        Bv[4] = fmaf(-bk, v1.x, Bv[4]); Bv[5] = fmaf(-bk, v1.y, Bv[5]);
        Bv[6] = fmaf(-bk, v1.z, Bv[6]); Bv[7] = fmaf(-bk, v1.w, Bv[7]);
        Bv[8] = fmaf(-bk, v2.x, Bv[8]); Bv[9] = fmaf(-bk, v2.y, Bv[9]);
    }

    // ---- per sum-bin product of (1 - min) == max(A_i, B_j): 2 ops/pair ----
    float prod[19];
    #pragma unroll
    for (int k = 0; k < 19; ++k) prod[k] = 1.0f;
    #pragma unroll
    for (int i = 0; i < 10; ++i) {
        #pragma unroll
        for (int j = 0; j < 10; ++j) {
            prod[i + j] *= fmaxf(A[i], Bv[j]);
        }
    }

    // ---- y = 1 - prod, normalize ----
    float y[19];
    float tot = 0.0f;
    #pragma unroll
    for (int k = 0; k < 19; ++k) { y[k] = 1.0f - prod[k]; tot += y[k]; }
    float inv = __builtin_amdgcn_rcpf(tot + 1e-9f);

    // ---- all input reads of s_buf are done block-wide before reuse ----
    __syncthreads();

    // ---- stage output in LDS (stride 19 odd -> 2-way aliasing, free) ----
    #pragma unroll
    for (int k = 0; k < 19; ++k) s_buf[t * 19 + k] = y[k] * inv;
    __syncthreads();

    {
        const float4* so = (const float4*)s_buf;               // 1216 float4
        float4* go = (float4*)(out + (size_t)blk * 4864);      // 19456 B, 16-aligned
        #pragma unroll
        for (int it = 0; it < 5; ++it) {
            int idx = t + it * 256;
            if (idx < 1216) go[idx] = so[idx];
        }
    }
}

extern "C" void kernel_launch(void* const* d_in, const int* in_sizes, int n_in,
                              void* d_out, int out_size, void* d_ws, size_t ws_size,
                              hipStream_t stream) {
    const float* p1 = (const float*)d_in[0];
    const float* p2 = (const float*)d_in[1];
    const float* W1 = (const float*)d_in[2];
    const float* W2 = (const float*)d_in[3];
    // d_in[4] = mask: bins are i+j, computed directly — mask unused.
    bacon_main<<<NBLOCKS, 256, 0, stream>>>(p1, p2, W1, W2, (float*)d_out);
}